// Round 12
// baseline (866.801 us; speedup 1.0000x reference)
//
#include <hip/hip_runtime.h>
#include <math.h>
#include <stdint.h>

#define NPOL 125
#define NANG 126
#define BB 32
#define CC 64
#define HH 128
#define WW 128
#define PIX (NPOL*NPOL)
#define PI_F 3.14159265358979323846f

typedef __attribute__((ext_vector_type(4))) float f32x4;
typedef _Float16 f16x8 __attribute__((ext_vector_type(8)));
union U16 { uint4 u; f16x8 v; };

// ---------------------------------------------------------------------------
// KZ: zero the scores accumulator (doubles; zero bit-pattern == 0.0).
// ---------------------------------------------------------------------------
__global__ __launch_bounds__(256) void kz_zero(float* __restrict__ p, int n) {
    int i = blockIdx.x * 256 + threadIdx.x;
    if (i < n) p[i] = 0.0f;
}

// Bilinear sample of a 128x128 LDS image at polar point u*(cv,sv), reference
// semantics (align_corners=True, zero padding via weight masks).
__device__ __forceinline__ float bil(const float* __restrict__ img, float u, float cv, float sv) {
    float x = u * cv, y = u * sv;
    float ix = (x + 1.0f) * 0.5f * 127.0f;
    float iy = (y + 1.0f) * 0.5f * 127.0f;
    float x0 = floorf(ix), y0 = floorf(iy);
    float wx1 = ix - x0, wy1 = iy - y0;
    float wx0 = 1.0f - wx1, wy0 = 1.0f - wy1;
    float mx0 = (x0 >= 0.0f && x0 <= 127.0f) ? wx0 : 0.0f;
    float mx1 = (x0 >= -1.0f && x0 <= 126.0f) ? wx1 : 0.0f;
    float my0 = (y0 >= 0.0f && y0 <= 127.0f) ? wy0 : 0.0f;
    float my1 = (y0 >= -1.0f && y0 <= 126.0f) ? wy1 : 0.0f;
    int xi0 = (int)fminf(fmaxf(x0, 0.0f), 127.0f);
    int xi1 = (int)fminf(fmaxf(x0 + 1.0f, 0.0f), 127.0f);
    int yi0 = (int)fminf(fmaxf(y0, 0.0f), 127.0f);
    int yi1 = (int)fminf(fmaxf(y0 + 1.0f, 0.0f), 127.0f);
    return my0 * (mx0 * img[yi0 * WW + xi0] + mx1 * img[yi0 * WW + xi1])
         + my1 * (mx0 * img[yi1 * WW + xi0] + mx1 * img[yi1 * WW + xi1]);
}

// ---------------------------------------------------------------------------
// K2 fused: polar-sample + correlation GEMM, no global intermediates.
// Block = (bp 0..15, kg 0..15): owns the closed plane set
//   A1=E1(bp,c) A2=E1(31-bp,63-c) B1=E2(bp,c) B2=E2(31-bp,63-c), c=kg*4+cl.
// Four M-phases per channel; ONE transient acc set (32 AGPRs) zeroed per
// phase, folded after each phase into per-thread part[4][5][4] f32 registers
// (the band mapping acc->t is thread-static). No persistent AGPR pressure ->
// no scratch spill. Reg-staged plane pipeline overlaps prefetch with sampling.
// Epilogue band-reduction in FP64. 512 thr = 8 waves (2M x 4N).
// ---------------------------------------------------------------------------
__global__ __launch_bounds__(512, 1) void k2_fused(const float* __restrict__ E1,
                                                   const float* __restrict__ E2,
                                                   double* __restrict__ scores) {
    __shared__ unsigned bufA[16384];   // 64 KB: raw f32 image, then fp16-split plane
    __shared__ unsigned bufB[16384];   // 64 KB
    __shared__ float tabU[128];
    __shared__ float tabC[128];
    __shared__ float tabS[128];
    __shared__ double sd[2][NANG];

    const int tid  = threadIdx.x;
    const int lane = tid & 63;
    const int wid  = tid >> 6;       // 0..7
    const int wm   = wid >> 2;       // 0..1  (M: rows wm*64..)
    const int wn   = wid & 3;        // 0..3  (N: i wn*32..)
    const int frow = lane & 15;
    const int kq   = lane >> 4;      // 0..3

    const int bp = blockIdx.x & 15;
    const int kg = blockIdx.x >> 4;

    if (tid < 128) {
        double dj = (double)tid;
        tabU[tid] = (tid < NPOL) ? (float)(dj * (1.4142135623730951 / 124.0)) : 0.0f;
        double v  = -3.14159265358979323846 + dj * (6.28318530717958647692 / 124.0);
        tabC[tid] = (tid < NPOL) ? (float)cos(v) : 0.0f;
        tabS[tid] = (tid < NPOL) ? (float)sin(v) : 0.0f;
    }
    if (tid < 2 * NANG) ((double*)sd)[tid] = 0.0;

    // Per-thread band partials: 4 phase-kinds x 5 diagonals x 4 rows.
    float part[4][5][4];
    #pragma unroll
    for (int s = 0; s < 4; ++s)
        #pragma unroll
        for (int d = 0; d < 5; ++d)
            #pragma unroll
            for (int r = 0; r < 4; ++r) part[s][d][r] = 0.0f;

    f32x4 acc[4][2];
    float4 stg[8];
    unsigned hw[16], lw[16];

    // Prologue: prefetch first plane (A1 of channel 0) into registers.
    {
        const float4* p0 = (const float4*)(E1 + (size_t)(bp * CC + kg * 4) * (HH * WW));
        #pragma unroll
        for (int k = 0; k < 8; ++k) stg[k] = p0[k * 512 + tid];
    }

// Write raw regs->BUF, issue NEXT plane's loads, sample BUF, write fp16 back.
#define LOADPLANE(BUF, NEXTP) do {                                              \
    _Pragma("unroll")                                                           \
    for (int k_ = 0; k_ < 8; ++k_) ((float4*)(BUF))[k_ * 512 + tid] = stg[k_];  \
    __syncthreads();                                                            \
    if (NEXTP) {                                                                \
        const float4* np_ = (const float4*)(NEXTP);                             \
        _Pragma("unroll")                                                       \
        for (int k_ = 0; k_ < 8; ++k_) stg[k_] = np_[k_ * 512 + tid];           \
    }                                                                           \
    {                                                                           \
        const float* f_ = (const float*)(BUF);                                  \
        _Pragma("unroll")                                                       \
        for (int it_ = 0; it_ < 16; ++it_) {                                    \
            int s_ = tid + it_ * 512;                                           \
            if (s_ < 8000) {                                                    \
                int r_ = s_ >> 6, p_ = s_ & 63;                                 \
                float cv_ = tabC[r_], sv_ = tabS[r_];                           \
                int j0_ = 2 * p_, j1_ = 2 * p_ + 1;                             \
                float va_ = bil(f_, tabU[j0_], cv_, sv_);                       \
                float vb_ = bil(f_, tabU[j1_], cv_, sv_);                       \
                if (j0_ >= NPOL) va_ = 0.0f;                                    \
                if (j1_ >= NPOL) vb_ = 0.0f;                                    \
                _Float16 h0_ = (_Float16)va_;                                   \
                _Float16 h1_ = (_Float16)vb_;                                   \
                _Float16 l0_ = (_Float16)(va_ - (float)h0_);                    \
                _Float16 l1_ = (_Float16)(vb_ - (float)h1_);                    \
                hw[it_] = (unsigned)__builtin_bit_cast(unsigned short, h0_)     \
                        | ((unsigned)__builtin_bit_cast(unsigned short, h1_) << 16); \
                lw[it_] = (unsigned)__builtin_bit_cast(unsigned short, l0_)     \
                        | ((unsigned)__builtin_bit_cast(unsigned short, l1_) << 16); \
            }                                                                   \
        }                                                                       \
    }                                                                           \
    __syncthreads();                                                            \
    _Pragma("unroll")                                                           \
    for (int it_ = 0; it_ < 16; ++it_) {                                        \
        int s_ = tid + it_ * 512;                                               \
        if (s_ < 8000) {                                                        \
            int r_ = s_ >> 6, p_ = s_ & 63;                                     \
            int ih_ = (r_ * 128 + p_) ^ ((r_ & 7) << 2);                        \
            (BUF)[ih_]      = hw[it_];                                          \
            (BUF)[ih_ + 64] = lw[it_];                                          \
        }                                                                       \
    }                                                                           \
    if (tid < 384) {                                                            \
        int rr_ = 125 + (tid >> 7), pp_ = tid & 127;                            \
        (BUF)[rr_ * 128 + pp_] = 0u;                                            \
    }                                                                           \
    __syncthreads();                                                            \
} while (0)

// One 128x128x128 3-pass split-fp16 MFMA phase into the transient acc,
// then fold into part[SET]. acc is zeroed at phase start.
#define MPHASE(SET) do {                                                        \
    _Pragma("unroll")                                                           \
    for (int mi_ = 0; mi_ < 4; ++mi_)                                           \
        _Pragma("unroll")                                                       \
        for (int ni_ = 0; ni_ < 2; ++ni_) acc[mi_][ni_] = (f32x4){0.f,0.f,0.f,0.f}; \
    _Pragma("unroll")                                                           \
    for (int jc_ = 0; jc_ < 4; ++jc_) {                                         \
        U16 bh_[2], bl_[2];                                                     \
        _Pragma("unroll")                                                       \
        for (int ni_ = 0; ni_ < 2; ++ni_) {                                     \
            int row_ = wn * 32 + ni_ * 16 + frow;                               \
            int idx_ = (row_ * 128 + jc_ * 16 + kq * 4) ^ ((row_ & 7) << 2);    \
            bh_[ni_].u = *(const uint4*)(bufB + idx_);                          \
            bl_[ni_].u = *(const uint4*)(bufB + idx_ + 64);                     \
        }                                                                       \
        _Pragma("unroll")                                                       \
        for (int mi_ = 0; mi_ < 4; ++mi_) {                                     \
            int row_ = wm * 64 + mi_ * 16 + frow;                               \
            int idx_ = (row_ * 128 + jc_ * 16 + kq * 4) ^ ((row_ & 7) << 2);    \
            U16 ah_, al_;                                                       \
            ah_.u = *(const uint4*)(bufA + idx_);                               \
            al_.u = *(const uint4*)(bufA + idx_ + 64);                          \
            _Pragma("unroll")                                                   \
            for (int ni_ = 0; ni_ < 2; ++ni_) {                                 \
                acc[mi_][ni_] = __builtin_amdgcn_mfma_f32_16x16x32_f16(ah_.v, bh_[ni_].v, acc[mi_][ni_], 0, 0, 0); \
                acc[mi_][ni_] = __builtin_amdgcn_mfma_f32_16x16x32_f16(ah_.v, bl_[ni_].v, acc[mi_][ni_], 0, 0, 0); \
                acc[mi_][ni_] = __builtin_amdgcn_mfma_f32_16x16x32_f16(al_.v, bh_[ni_].v, acc[mi_][ni_], 0, 0, 0); \
            }                                                                   \
        }                                                                       \
    }                                                                           \
    _Pragma("unroll")                                                           \
    for (int mi_ = 0; mi_ < 4; ++mi_)                                           \
        _Pragma("unroll")                                                       \
        for (int ni_ = 0; ni_ < 2; ++ni_) {                                     \
            int d_ = mi_ - ni_ + 1;                                             \
            _Pragma("unroll")                                                   \
            for (int r_ = 0; r_ < 4; ++r_) part[SET][d_][r_] += acc[mi_][ni_][r_]; \
        }                                                                       \
} while (0)

    for (int cl = 0; cl < 4; ++cl) {
        const int c  = kg * 4 + cl;
        const int cb = 63 - c;
        const float* pA1 = E1 + (size_t)(bp * CC + c) * (HH * WW);
        const float* pA2 = E1 + (size_t)((31 - bp) * CC + cb) * (HH * WW);
        const float* pB1 = E2 + (size_t)(bp * CC + c) * (HH * WW);
        const float* pB2 = E2 + (size_t)((31 - bp) * CC + cb) * (HH * WW);
        const float* pNx = (cl < 3) ? (pA1 + HH * WW) : nullptr;

        // stg holds raw A1 on entry.
        LOADPLANE(bufA, pB1);     // A1 -> bufA, prefetch B1
        LOADPLANE(bufB, pA2);     // B1 -> bufB, prefetch A2
        MPHASE(0);                // A1 x B1   (b,  t = r-i)
        __syncthreads();
        LOADPLANE(bufA, pB2);     // A2 -> bufA, prefetch B2
        MPHASE(1);                // A2 x B1   (b,  t = 125+r-i)
        __syncthreads();
        LOADPLANE(bufB, pA1);     // B2 -> bufB, prefetch A1 (L2-hot)
        MPHASE(2);                // A2 x B2   (b~, t = r-i)
        __syncthreads();
        LOADPLANE(bufA, pNx);     // A1 -> bufA, prefetch next channel's A1
        MPHASE(3);                // A1 x B2   (b~, t = 125+r-i)
        __syncthreads();
    }

    // Band-reduce the 4 part sets in FP64: t = TOFF + tb + (d-1)*16 + r.
#define EPI(SET, SDI, TOFF) do {                                                \
    int tb_ = (TOFF) + wm * 64 - wn * 32 + ((lane >> 4) << 2) - (lane & 15);    \
    _Pragma("unroll")                                                           \
    for (int d_ = 0; d_ < 5; ++d_)                                              \
        _Pragma("unroll")                                                       \
        for (int r_ = 0; r_ < 4; ++r_) {                                        \
            int t_ = tb_ + (d_ - 1) * 16 + r_;                                  \
            if (t_ >= 0 && t_ < NANG) atomicAdd(&sd[SDI][t_], (double)part[SET][d_][r_]); \
        }                                                                       \
} while (0)

    EPI(0, 0, 0);
    EPI(1, 0, 125);
    EPI(2, 1, 0);
    EPI(3, 1, 125);
    __syncthreads();
    if (tid < 2 * NANG) {
        int o = (tid < NANG) ? 0 : 1;
        int t = tid - o * NANG;
        int b = o ? (31 - bp) : bp;
        atomicAdd(&scores[b * NANG + t], sd[o][t]);
    }
#undef LOADPLANE
#undef MPHASE
#undef EPI
}

// ---------------------------------------------------------------------------
// K3: softmax over t, theta -> Mat, all in FP64. One block per b.
// ---------------------------------------------------------------------------
__global__ __launch_bounds__(128) void k3_theta(const double* __restrict__ scores, float* __restrict__ matOut) {
    const int b = blockIdx.x;
    const int t = threadIdx.x;   // 0..127
    __shared__ double sd[128];
    __shared__ double red[128];

    double sval = (t < NANG) ? scores[b * NANG + t] : -1e300;
    sd[t]  = sval;
    red[t] = sval;
    __syncthreads();
    for (int st = 64; st > 0; st >>= 1) {
        if (t < st) red[t] = fmax(red[t], red[t + st]);
        __syncthreads();
    }
    const double m = red[0];
    __syncthreads();
    const double e = (t < NANG) ? exp(sd[t] - m) : 0.0;
    red[t] = e;
    __syncthreads();
    for (int st = 64; st > 0; st >>= 1) {
        if (t < st) red[t] += red[t + st];
        __syncthreads();
    }
    const double Z = red[0];
    __syncthreads();
    const double ang = -3.14159265358979323846 + (double)t * (6.28318530717958647692 / 125.0);
    red[t] = e * ang;
    __syncthreads();
    for (int st = 64; st > 0; st >>= 1) {
        if (t < st) red[t] += red[t + st];
        __syncthreads();
    }
    if (t == 0) {
        double theta = red[0] / Z - 3.14159265358979323846;
        float cth = (float)cos(theta), sth = (float)sin(theta);
        float* M = matOut + b * 6;
        M[0] = cth; M[1] = -sth; M[2] = 0.0f;
        M[3] = sth; M[4] = cth;  M[5] = 0.0f;
    }
}

// ---------------------------------------------------------------------------
// K4: affine grid + grid_sample of Embd1. One block per (b,c) plane.
// ---------------------------------------------------------------------------
__global__ __launch_bounds__(512) void k4_affine(const float* __restrict__ img, const float* __restrict__ mat,
                                                 float* __restrict__ out) {
    __shared__ float plane[HH * WW];
    const int bc  = blockIdx.x;
    const int b   = bc >> 6;
    const int tid = threadIdx.x;
    const float4* src = (const float4*)img + (size_t)bc * (HH * WW / 4);
    float4* d4 = (float4*)plane;
    #pragma unroll
    for (int it = 0; it < 8; ++it) d4[it * 512 + tid] = src[it * 512 + tid];
    __syncthreads();
    const float M0 = mat[b * 6 + 0], M1 = mat[b * 6 + 1];
    const float M3 = mat[b * 6 + 3], M4 = mat[b * 6 + 4];
    const int base = bc * PIX;
    for (int pix = tid; pix < PIX; pix += 512) {
        int i = pix / NPOL;
        int j = pix - i * NPOL;
        float xx = (float)(-1.0 + (double)j * (2.0 / 124.0));
        float yy = (float)(-1.0 + (double)i * (2.0 / 124.0));
        float gx = M0 * xx + M1 * yy;
        float gy = M3 * xx + M4 * yy;
        float ix = (gx + 1.0f) * 0.5f * 127.0f;
        float iy = (gy + 1.0f) * 0.5f * 127.0f;
        float x0 = floorf(ix), y0 = floorf(iy);
        float wx1 = ix - x0, wy1 = iy - y0;
        float wx0 = 1.0f - wx1, wy0 = 1.0f - wy1;
        float mx0 = (x0 >= 0.0f && x0 <= 127.0f) ? wx0 : 0.0f;
        float mx1 = (x0 >= -1.0f && x0 <= 126.0f) ? wx1 : 0.0f;
        float my0 = (y0 >= 0.0f && y0 <= 127.0f) ? wy0 : 0.0f;
        float my1 = (y0 >= -1.0f && y0 <= 126.0f) ? wy1 : 0.0f;
        int xi0 = (int)fminf(fmaxf(x0, 0.0f), 127.0f);
        int xi1 = (int)fminf(fmaxf(x0 + 1.0f, 0.0f), 127.0f);
        int yi0 = (int)fminf(fmaxf(y0, 0.0f), 127.0f);
        int yi1 = (int)fminf(fmaxf(y0 + 1.0f, 0.0f), 127.0f);
        float val = my0 * (mx0 * plane[yi0 * WW + xi0] + mx1 * plane[yi0 * WW + xi1])
                  + my1 * (mx0 * plane[yi1 * WW + xi0] + mx1 * plane[yi1 * WW + xi1]);
        out[base + pix] = val;
    }
}

// ---------------------------------------------------------------------------
// Launch. d_out: image [32M f32] | Mat [192 f32]. ws: scores (4032 f64).
// ---------------------------------------------------------------------------
extern "C" void kernel_launch(void* const* d_in, const int* in_sizes, int n_in,
                              void* d_out, int out_size, void* d_ws, size_t ws_size,
                              hipStream_t stream) {
    const float* E1 = (const float*)d_in[0];
    const float* E2 = (const float*)d_in[1];
    float*  out    = (float*)d_out;
    float*  matOut = out + 32000000;
    double* scores = (double*)d_ws;

    kz_zero<<<(2 * BB * NANG + 255) / 256, 256, 0, stream>>>((float*)scores, 2 * BB * NANG);
    k2_fused<<<256, 512, 0, stream>>>(E1, E2, scores);
    k3_theta<<<BB, 128, 0, stream>>>(scores, matOut);
    k4_affine<<<BB * CC, 512, 0, stream>>>(E1, matOut, out);
}

// Round 13
// 395.783 us; speedup vs baseline: 2.1901x; 2.1901x over previous
//
#include <hip/hip_runtime.h>
#include <math.h>
#include <stdint.h>

#define NPOL 125
#define NANG 126
#define BB 32
#define CC 64
#define HH 128
#define WW 128
#define PIX (NPOL*NPOL)
#define PI_F 3.14159265358979323846f

typedef __attribute__((ext_vector_type(4))) float f32x4;
typedef _Float16 f16x8 __attribute__((ext_vector_type(8)));
union U16 { uint4 u; f16x8 v; };

// ---------------------------------------------------------------------------
// KZ: zero the scores accumulator (doubles; zero bit-pattern == 0.0).
// ---------------------------------------------------------------------------
__global__ __launch_bounds__(256) void kz_zero(float* __restrict__ p, int n) {
    int i = blockIdx.x * 256 + threadIdx.x;
    if (i < n) p[i] = 0.0f;
}

// Bilinear sample of a 128x128 LDS image at polar point u*(cv,sv), reference
// semantics (align_corners=True, zero padding via weight masks).
__device__ __forceinline__ float bil(const float* __restrict__ img, float u, float cv, float sv) {
    float x = u * cv, y = u * sv;
    float ix = (x + 1.0f) * 0.5f * 127.0f;
    float iy = (y + 1.0f) * 0.5f * 127.0f;
    float x0 = floorf(ix), y0 = floorf(iy);
    float wx1 = ix - x0, wy1 = iy - y0;
    float wx0 = 1.0f - wx1, wy0 = 1.0f - wy1;
    float mx0 = (x0 >= 0.0f && x0 <= 127.0f) ? wx0 : 0.0f;
    float mx1 = (x0 >= -1.0f && x0 <= 126.0f) ? wx1 : 0.0f;
    float my0 = (y0 >= 0.0f && y0 <= 127.0f) ? wy0 : 0.0f;
    float my1 = (y0 >= -1.0f && y0 <= 126.0f) ? wy1 : 0.0f;
    int xi0 = (int)fminf(fmaxf(x0, 0.0f), 127.0f);
    int xi1 = (int)fminf(fmaxf(x0 + 1.0f, 0.0f), 127.0f);
    int yi0 = (int)fminf(fmaxf(y0, 0.0f), 127.0f);
    int yi1 = (int)fminf(fmaxf(y0 + 1.0f, 0.0f), 127.0f);
    return my0 * (mx0 * img[yi0 * WW + xi0] + mx1 * img[yi0 * WW + xi1])
         + my1 * (mx0 * img[yi1 * WW + xi0] + mx1 * img[yi1 * WW + xi1]);
}

// ---------------------------------------------------------------------------
// K2 fused: polar-sample + correlation GEMM, no global intermediates.
// Block = (bp 0..15, kg 0..15): owns the closed plane set
//   A1=E1(bp,c) A2=E1(31-bp,63-c) B1=E2(bp,c) B2=E2(31-bp,63-c), c=kg*4+cl.
// Four M-phases per channel; ONE transient acc set (32 AGPRs) zeroed per
// phase; each phase's acc is folded IMMEDIATELY into the f64 LDS band
// accumulator sd (EPI-per-phase) -> zero persistent register state.
// Arch-VGPR working set (stg 32 + hw/lw 32 + temps) stays <= the 128-reg
// arch file the compiler pins when AGPRs are live -> no scratch spill.
// Reg-staged plane pipeline overlaps next-plane prefetch with sampling.
// 512 thr = 8 waves (2M x 4N), wave tile 64x32, 3-pass split-fp16 MFMA.
// ---------------------------------------------------------------------------
__global__ __launch_bounds__(512, 1) void k2_fused(const float* __restrict__ E1,
                                                   const float* __restrict__ E2,
                                                   double* __restrict__ scores) {
    __shared__ unsigned bufA[16384];   // 64 KB: raw f32 image, then fp16-split plane
    __shared__ unsigned bufB[16384];   // 64 KB
    __shared__ float tabU[128];
    __shared__ float tabC[128];
    __shared__ float tabS[128];
    __shared__ double sd[2][NANG];

    const int tid  = threadIdx.x;
    const int lane = tid & 63;
    const int wid  = tid >> 6;       // 0..7
    const int wm   = wid >> 2;       // 0..1  (M: rows wm*64..)
    const int wn   = wid & 3;        // 0..3  (N: i wn*32..)
    const int frow = lane & 15;
    const int kq   = lane >> 4;      // 0..3

    const int bp = blockIdx.x & 15;
    const int kg = blockIdx.x >> 4;

    if (tid < 128) {
        double dj = (double)tid;
        tabU[tid] = (tid < NPOL) ? (float)(dj * (1.4142135623730951 / 124.0)) : 0.0f;
        double v  = -3.14159265358979323846 + dj * (6.28318530717958647692 / 124.0);
        tabC[tid] = (tid < NPOL) ? (float)cos(v) : 0.0f;
        tabS[tid] = (tid < NPOL) ? (float)sin(v) : 0.0f;
    }
    if (tid < 2 * NANG) ((double*)sd)[tid] = 0.0;

    f32x4 acc[4][2];
    float4 stg[8];
    unsigned hw[16], lw[16];

    // Prologue: prefetch first plane (A1 of channel 0) into registers.
    {
        const float4* p0 = (const float4*)(E1 + (size_t)(bp * CC + kg * 4) * (HH * WW));
        #pragma unroll
        for (int k = 0; k < 8; ++k) stg[k] = p0[k * 512 + tid];
    }

// Write raw regs->BUF, issue NEXT plane's loads, sample BUF, write fp16 back.
#define LOADPLANE(BUF, NEXTP) do {                                              \
    _Pragma("unroll")                                                           \
    for (int k_ = 0; k_ < 8; ++k_) ((float4*)(BUF))[k_ * 512 + tid] = stg[k_];  \
    __syncthreads();                                                            \
    if (NEXTP) {                                                                \
        const float4* np_ = (const float4*)(NEXTP);                             \
        _Pragma("unroll")                                                       \
        for (int k_ = 0; k_ < 8; ++k_) stg[k_] = np_[k_ * 512 + tid];           \
    }                                                                           \
    {                                                                           \
        const float* f_ = (const float*)(BUF);                                  \
        _Pragma("unroll")                                                       \
        for (int it_ = 0; it_ < 16; ++it_) {                                    \
            int s_ = tid + it_ * 512;                                           \
            if (s_ < 8000) {                                                    \
                int r_ = s_ >> 6, p_ = s_ & 63;                                 \
                float cv_ = tabC[r_], sv_ = tabS[r_];                           \
                int j0_ = 2 * p_, j1_ = 2 * p_ + 1;                             \
                float va_ = bil(f_, tabU[j0_], cv_, sv_);                       \
                float vb_ = bil(f_, tabU[j1_], cv_, sv_);                       \
                if (j0_ >= NPOL) va_ = 0.0f;                                    \
                if (j1_ >= NPOL) vb_ = 0.0f;                                    \
                _Float16 h0_ = (_Float16)va_;                                   \
                _Float16 h1_ = (_Float16)vb_;                                   \
                _Float16 l0_ = (_Float16)(va_ - (float)h0_);                    \
                _Float16 l1_ = (_Float16)(vb_ - (float)h1_);                    \
                hw[it_] = (unsigned)__builtin_bit_cast(unsigned short, h0_)     \
                        | ((unsigned)__builtin_bit_cast(unsigned short, h1_) << 16); \
                lw[it_] = (unsigned)__builtin_bit_cast(unsigned short, l0_)     \
                        | ((unsigned)__builtin_bit_cast(unsigned short, l1_) << 16); \
            }                                                                   \
        }                                                                       \
    }                                                                           \
    __syncthreads();                                                            \
    _Pragma("unroll")                                                           \
    for (int it_ = 0; it_ < 16; ++it_) {                                        \
        int s_ = tid + it_ * 512;                                               \
        if (s_ < 8000) {                                                        \
            int r_ = s_ >> 6, p_ = s_ & 63;                                     \
            int ih_ = (r_ * 128 + p_) ^ ((r_ & 7) << 2);                        \
            (BUF)[ih_]      = hw[it_];                                          \
            (BUF)[ih_ + 64] = lw[it_];                                          \
        }                                                                       \
    }                                                                           \
    if (tid < 384) {                                                            \
        int rr_ = 125 + (tid >> 7), pp_ = tid & 127;                            \
        (BUF)[rr_ * 128 + pp_] = 0u;                                            \
    }                                                                           \
    __syncthreads();                                                            \
} while (0)

// One 128x128x128 3-pass split-fp16 MFMA phase into the transient acc
// (zeroed at phase start): bufA (M rows) x bufB (N rows).
#define MPHASE() do {                                                           \
    _Pragma("unroll")                                                           \
    for (int mi_ = 0; mi_ < 4; ++mi_)                                           \
        _Pragma("unroll")                                                       \
        for (int ni_ = 0; ni_ < 2; ++ni_) acc[mi_][ni_] = (f32x4){0.f,0.f,0.f,0.f}; \
    _Pragma("unroll")                                                           \
    for (int jc_ = 0; jc_ < 4; ++jc_) {                                         \
        U16 bh_[2], bl_[2];                                                     \
        _Pragma("unroll")                                                       \
        for (int ni_ = 0; ni_ < 2; ++ni_) {                                     \
            int row_ = wn * 32 + ni_ * 16 + frow;                               \
            int idx_ = (row_ * 128 + jc_ * 16 + kq * 4) ^ ((row_ & 7) << 2);    \
            bh_[ni_].u = *(const uint4*)(bufB + idx_);                          \
            bl_[ni_].u = *(const uint4*)(bufB + idx_ + 64);                     \
        }                                                                       \
        _Pragma("unroll")                                                       \
        for (int mi_ = 0; mi_ < 4; ++mi_) {                                     \
            int row_ = wm * 64 + mi_ * 16 + frow;                               \
            int idx_ = (row_ * 128 + jc_ * 16 + kq * 4) ^ ((row_ & 7) << 2);    \
            U16 ah_, al_;                                                       \
            ah_.u = *(const uint4*)(bufA + idx_);                               \
            al_.u = *(const uint4*)(bufA + idx_ + 64);                          \
            _Pragma("unroll")                                                   \
            for (int ni_ = 0; ni_ < 2; ++ni_) {                                 \
                acc[mi_][ni_] = __builtin_amdgcn_mfma_f32_16x16x32_f16(ah_.v, bh_[ni_].v, acc[mi_][ni_], 0, 0, 0); \
                acc[mi_][ni_] = __builtin_amdgcn_mfma_f32_16x16x32_f16(ah_.v, bl_[ni_].v, acc[mi_][ni_], 0, 0, 0); \
                acc[mi_][ni_] = __builtin_amdgcn_mfma_f32_16x16x32_f16(al_.v, bh_[ni_].v, acc[mi_][ni_], 0, 0, 0); \
            }                                                                   \
        }                                                                       \
    }                                                                           \
} while (0)

// Fold transient acc into the f64 LDS band accumulator: t = TOFF + tb +
// (mi-ni)*16 + r. Transient part5 keeps the atomic count at 20/thread.
#define EPIP(SDI, TOFF) do {                                                    \
    float part5_[5][4];                                                         \
    _Pragma("unroll")                                                           \
    for (int d_ = 0; d_ < 5; ++d_)                                              \
        _Pragma("unroll")                                                       \
        for (int r_ = 0; r_ < 4; ++r_) part5_[d_][r_] = 0.0f;                   \
    _Pragma("unroll")                                                           \
    for (int mi_ = 0; mi_ < 4; ++mi_)                                           \
        _Pragma("unroll")                                                       \
        for (int ni_ = 0; ni_ < 2; ++ni_) {                                     \
            int d_ = mi_ - ni_ + 1;                                             \
            _Pragma("unroll")                                                   \
            for (int r_ = 0; r_ < 4; ++r_) part5_[d_][r_] += acc[mi_][ni_][r_]; \
        }                                                                       \
    int tb_ = (TOFF) + wm * 64 - wn * 32 + ((lane >> 4) << 2) - (lane & 15);    \
    _Pragma("unroll")                                                           \
    for (int d_ = 0; d_ < 5; ++d_)                                              \
        _Pragma("unroll")                                                       \
        for (int r_ = 0; r_ < 4; ++r_) {                                        \
            int t_ = tb_ + (d_ - 1) * 16 + r_;                                  \
            if (t_ >= 0 && t_ < NANG) atomicAdd(&sd[SDI][t_], (double)part5_[d_][r_]); \
        }                                                                       \
} while (0)

    for (int cl = 0; cl < 4; ++cl) {
        const int c  = kg * 4 + cl;
        const int cb = 63 - c;
        const float* pA1 = E1 + (size_t)(bp * CC + c) * (HH * WW);
        const float* pA2 = E1 + (size_t)((31 - bp) * CC + cb) * (HH * WW);
        const float* pB1 = E2 + (size_t)(bp * CC + c) * (HH * WW);
        const float* pB2 = E2 + (size_t)((31 - bp) * CC + cb) * (HH * WW);
        const float* pNx = (cl < 3) ? (pA1 + HH * WW) : nullptr;

        // stg holds raw A1 on entry.
        LOADPLANE(bufA, pB1);     // A1 -> bufA, prefetch B1
        LOADPLANE(bufB, pA2);     // B1 -> bufB, prefetch A2
        MPHASE(); EPIP(0, 0);     // A1 x B1   (b,  t = r-i)
        __syncthreads();
        LOADPLANE(bufA, pB2);     // A2 -> bufA, prefetch B2
        MPHASE(); EPIP(0, 125);   // A2 x B1   (b,  t = 125+r-i)
        __syncthreads();
        LOADPLANE(bufB, pA1);     // B2 -> bufB, prefetch A1 (L2-hot)
        MPHASE(); EPIP(1, 0);     // A2 x B2   (b~, t = r-i)
        __syncthreads();
        LOADPLANE(bufA, pNx);     // A1 -> bufA, prefetch next channel's A1
        MPHASE(); EPIP(1, 125);   // A1 x B2   (b~, t = 125+r-i)
        __syncthreads();
    }

    __syncthreads();
    if (tid < 2 * NANG) {
        int o = (tid < NANG) ? 0 : 1;
        int t = tid - o * NANG;
        int b = o ? (31 - bp) : bp;
        atomicAdd(&scores[b * NANG + t], sd[o][t]);
    }
#undef LOADPLANE
#undef MPHASE
#undef EPIP
}

// ---------------------------------------------------------------------------
// K3: softmax over t, theta -> Mat, all in FP64. One block per b.
// ---------------------------------------------------------------------------
__global__ __launch_bounds__(128) void k3_theta(const double* __restrict__ scores, float* __restrict__ matOut) {
    const int b = blockIdx.x;
    const int t = threadIdx.x;   // 0..127
    __shared__ double sd[128];
    __shared__ double red[128];

    double sval = (t < NANG) ? scores[b * NANG + t] : -1e300;
    sd[t]  = sval;
    red[t] = sval;
    __syncthreads();
    for (int st = 64; st > 0; st >>= 1) {
        if (t < st) red[t] = fmax(red[t], red[t + st]);
        __syncthreads();
    }
    const double m = red[0];
    __syncthreads();
    const double e = (t < NANG) ? exp(sd[t] - m) : 0.0;
    red[t] = e;
    __syncthreads();
    for (int st = 64; st > 0; st >>= 1) {
        if (t < st) red[t] += red[t + st];
        __syncthreads();
    }
    const double Z = red[0];
    __syncthreads();
    const double ang = -3.14159265358979323846 + (double)t * (6.28318530717958647692 / 125.0);
    red[t] = e * ang;
    __syncthreads();
    for (int st = 64; st > 0; st >>= 1) {
        if (t < st) red[t] += red[t + st];
        __syncthreads();
    }
    if (t == 0) {
        double theta = red[0] / Z - 3.14159265358979323846;
        float cth = (float)cos(theta), sth = (float)sin(theta);
        float* M = matOut + b * 6;
        M[0] = cth; M[1] = -sth; M[2] = 0.0f;
        M[3] = sth; M[4] = cth;  M[5] = 0.0f;
    }
}

// ---------------------------------------------------------------------------
// K4: affine grid + grid_sample of Embd1. One block per (b,c) plane.
// ---------------------------------------------------------------------------
__global__ __launch_bounds__(512) void k4_affine(const float* __restrict__ img, const float* __restrict__ mat,
                                                 float* __restrict__ out) {
    __shared__ float plane[HH * WW];
    const int bc  = blockIdx.x;
    const int b   = bc >> 6;
    const int tid = threadIdx.x;
    const float4* src = (const float4*)img + (size_t)bc * (HH * WW / 4);
    float4* d4 = (float4*)plane;
    #pragma unroll
    for (int it = 0; it < 8; ++it) d4[it * 512 + tid] = src[it * 512 + tid];
    __syncthreads();
    const float M0 = mat[b * 6 + 0], M1 = mat[b * 6 + 1];
    const float M3 = mat[b * 6 + 3], M4 = mat[b * 6 + 4];
    const int base = bc * PIX;
    for (int pix = tid; pix < PIX; pix += 512) {
        int i = pix / NPOL;
        int j = pix - i * NPOL;
        float xx = (float)(-1.0 + (double)j * (2.0 / 124.0));
        float yy = (float)(-1.0 + (double)i * (2.0 / 124.0));
        float gx = M0 * xx + M1 * yy;
        float gy = M3 * xx + M4 * yy;
        float ix = (gx + 1.0f) * 0.5f * 127.0f;
        float iy = (gy + 1.0f) * 0.5f * 127.0f;
        float x0 = floorf(ix), y0 = floorf(iy);
        float wx1 = ix - x0, wy1 = iy - y0;
        float wx0 = 1.0f - wx1, wy0 = 1.0f - wy1;
        float mx0 = (x0 >= 0.0f && x0 <= 127.0f) ? wx0 : 0.0f;
        float mx1 = (x0 >= -1.0f && x0 <= 126.0f) ? wx1 : 0.0f;
        float my0 = (y0 >= 0.0f && y0 <= 127.0f) ? wy0 : 0.0f;
        float my1 = (y0 >= -1.0f && y0 <= 126.0f) ? wy1 : 0.0f;
        int xi0 = (int)fminf(fmaxf(x0, 0.0f), 127.0f);
        int xi1 = (int)fminf(fmaxf(x0 + 1.0f, 0.0f), 127.0f);
        int yi0 = (int)fminf(fmaxf(y0, 0.0f), 127.0f);
        int yi1 = (int)fminf(fmaxf(y0 + 1.0f, 0.0f), 127.0f);
        float val = my0 * (mx0 * plane[yi0 * WW + xi0] + mx1 * plane[yi0 * WW + xi1])
                  + my1 * (mx0 * plane[yi1 * WW + xi0] + mx1 * plane[yi1 * WW + xi1]);
        out[base + pix] = val;
    }
}

// ---------------------------------------------------------------------------
// Launch. d_out: image [32M f32] | Mat [192 f32]. ws: scores (4032 f64).
// ---------------------------------------------------------------------------
extern "C" void kernel_launch(void* const* d_in, const int* in_sizes, int n_in,
                              void* d_out, int out_size, void* d_ws, size_t ws_size,
                              hipStream_t stream) {
    const float* E1 = (const float*)d_in[0];
    const float* E2 = (const float*)d_in[1];
    float*  out    = (float*)d_out;
    float*  matOut = out + 32000000;
    double* scores = (double*)d_ws;

    kz_zero<<<(2 * BB * NANG + 255) / 256, 256, 0, stream>>>((float*)scores, 2 * BB * NANG);
    k2_fused<<<256, 512, 0, stream>>>(E1, E2, scores);
    k3_theta<<<BB, 128, 0, stream>>>(scores, matOut);
    k4_affine<<<BB * CC, 512, 0, stream>>>(E1, matOut, out);
}